// Round 3
// baseline (196.759 us; speedup 1.0000x reference)
//
#include <hip/hip_runtime.h>
#include <math.h>

#define N_NODES 50000
#define N_EDGES 800000
#define NFEAT 256
#define NHID 64
#define NCLASS 2

// buckets: node>>6 -> 782 buckets of 64 nodes
#define DB 64
#define NDB 782
#define BCAP 1536        // mean 1024, sigma 32 -> +16 sigma headroom
#define EPB 2048         // edges per scatter block (8/thread) -> 391 blocks
#define NB_EDGE ((N_EDGES + EPB - 1) / EPB)
#define CSTRIDE 32       // cursors padded: 1 counter per 128B line

// ---------------- workspace layout (4-byte units) ----------------
#define OFF_CURD 0        // int[NDB*CSTRIDE=25024] dst-bucket cursors
#define OFF_CURS 25024    // int[NDB*CSTRIDE=25024] src-bucket cursors
#define OFF_RBD  50048    // int2[50000] (row_beg, deg)
#define OFF_NDST 150048   // f32[50000]
#define OFF_NSRC 200048   // f32[50000]
#define OFF_W1T  250048   // bf16[64*256] = 8192 words
#define OFF_DPK  258240   // int[782*1536=1201152] packed (src<<6|dst&63); csr aliases this
#define OFF_SV6  1459392  // uchar[1201152] (src&63) by src>>6 = 300288 words
#define OFF_HB   1759680  // bf16[50000*64] = 1600000 dwords (norm_src-scaled x@W1)
#define OFF_H2   3359680  // f32[100000]

typedef __attribute__((ext_vector_type(8))) short bf16x8;
typedef __attribute__((ext_vector_type(4))) float f32x4;

static __device__ __forceinline__ unsigned short f2bf(float f) {
    union { float f; unsigned int u; } v; v.f = f;
    return (unsigned short)((v.u + 0x8000u) >> 16);
}
static __device__ __forceinline__ unsigned int pk2bf(float f0, float f1) {
    union { float f; unsigned int u; } a, b; a.f = f0; b.f = f1;
    return __builtin_amdgcn_perm(b.u + 0x8000u, a.u + 0x8000u, 0x07060302u);
}
static __device__ __forceinline__ float bflo(unsigned int u) {
    union { unsigned int x; float f; } v; v.x = u << 16; return v.f;
}
static __device__ __forceinline__ float bfhi(unsigned int u) {
    union { unsigned int x; float f; } v; v.x = u & 0xffff0000u; return v.f;
}

// K0: zero cursor arrays (cur_d + cur_s contiguous), W1 -> W1T bf16
#define INIT_CUR (2 * NDB * CSTRIDE)
#define INIT_N (INIT_CUR + NFEAT * NHID)
__global__ __launch_bounds__(256) void init_kernel(const float* __restrict__ W1,
                                                   int* __restrict__ cursors,
                                                   unsigned short* __restrict__ w1t) {
    int g = blockIdx.x * 256 + threadIdx.x;
    if (g < INIT_CUR) {
        cursors[g] = 0;
    } else if (g < INIT_N) {
        int idx = g - INIT_CUR;
        int k = idx >> 6, n = idx & 63;
        w1t[n * NFEAT + k] = f2bf(W1[idx]);
    }
}

// K1: scatter — partition edges into dst-buckets (packed src<<6|dstlow) AND
//     src-buckets (src&63 bytes, for out-degree). LDS atomics for hist/pos;
//     global cursor atomics batched: all 8 issued before any result consumed.
struct SgShared { int hd[NDB], bd[NDB], cd[NDB], hs[NDB], bs[NDB], cs[NDB]; };  // 18.8 KB
__global__ __launch_bounds__(256) void scatter_kernel(const int* __restrict__ src,
                                                      const int* __restrict__ dst,
                                                      int* __restrict__ cur_d,
                                                      int* __restrict__ cur_s,
                                                      int* __restrict__ dpk,
                                                      unsigned char* __restrict__ sv6) {
    __shared__ SgShared su;
    int t = threadIdx.x;
    for (int i = t; i < NDB; i += 256) { su.hd[i] = 0; su.cd[i] = 0; su.hs[i] = 0; su.cs[i] = 0; }
    __syncthreads();
    int base = blockIdx.x * EPB;
    int ls[8], ld[8];
#pragma unroll
    for (int i = 0; i < 8; ++i) {
        int e = base + t + i * 256;
        ls[i] = (e < N_EDGES) ? src[e] : -1;
        ld[i] = (e < N_EDGES) ? dst[e] : -1;
        if (ld[i] >= 0) {
            atomicAdd(&su.hd[ld[i] >> 6], 1);
            atomicAdd(&su.hs[ls[i] >> 6], 1);
        }
    }
    __syncthreads();
    // batched cursor atomics: slots t, t+256, t+512 (all < 782), t+768 (t<14)
    {
        int i0 = t, i1 = t + 256, i2 = t + 512, i3 = t + 768;
        int hd0 = su.hd[i0], hs0 = su.hs[i0];
        int hd1 = su.hd[i1], hs1 = su.hs[i1];
        int hd2 = su.hd[i2], hs2 = su.hs[i2];
        int hd3 = (i3 < NDB) ? su.hd[i3] : 0;
        int hs3 = (i3 < NDB) ? su.hs[i3] : 0;
        int b0 = 0, b1v = 0, b2v = 0, b3v = 0, c0 = 0, c1v = 0, c2v = 0, c3v = 0;
        if (hd0) b0  = atomicAdd(&cur_d[i0 * CSTRIDE], hd0);
        if (hs0) c0  = atomicAdd(&cur_s[i0 * CSTRIDE], hs0);
        if (hd1) b1v = atomicAdd(&cur_d[i1 * CSTRIDE], hd1);
        if (hs1) c1v = atomicAdd(&cur_s[i1 * CSTRIDE], hs1);
        if (hd2) b2v = atomicAdd(&cur_d[i2 * CSTRIDE], hd2);
        if (hs2) c2v = atomicAdd(&cur_s[i2 * CSTRIDE], hs2);
        if (hd3) b3v = atomicAdd(&cur_d[i3 * CSTRIDE], hd3);
        if (hs3) c3v = atomicAdd(&cur_s[i3 * CSTRIDE], hs3);
        su.bd[i0] = b0;  su.bs[i0] = c0;
        su.bd[i1] = b1v; su.bs[i1] = c1v;
        su.bd[i2] = b2v; su.bs[i2] = c2v;
        if (i3 < NDB) { su.bd[i3] = b3v; su.bs[i3] = c3v; }
    }
    __syncthreads();
#pragma unroll
    for (int i = 0; i < 8; ++i) {
        if (ld[i] >= 0) {
            int bin = ld[i] >> 6;
            int pos = su.bd[bin] + atomicAdd(&su.cd[bin], 1);
            dpk[bin * BCAP + pos] = (ls[i] << 6) | (ld[i] & 63);
            int sbin = ls[i] >> 6;
            int spos = su.bs[sbin] + atomicAdd(&su.cs[sbin], 1);
            sv6[sbin * BCAP + spos] = (unsigned char)(ls[i] & 63);
        }
    }
}

// K2: two roles:
//  role 0: sfin -- out-degree hist from sv6 -> norm_src
//  role 1: dfin -- CSR build (in-place over dpk) + norm_dst/rbdeg
union FinShared {
    struct { int ebuf[BCAP]; int hist4[256]; int hist[64]; int seg[64]; int cur[64]; } d;
    struct { int hist4[256]; } s;
};
__global__ __launch_bounds__(256) void fin_kernel(const int* __restrict__ cur_d,
                                                  const int* __restrict__ cur_s,
                                                  const int* __restrict__ dpk,
                                                  const unsigned char* __restrict__ sv6,
                                                  int2* __restrict__ rbdeg,
                                                  float* __restrict__ norm_dst,
                                                  float* __restrict__ norm_src,
                                                  int* __restrict__ csr) {
    __shared__ FinShared su;
    int t = threadIdx.x;
    int role = blockIdx.x & 1;
    int b = blockIdx.x >> 1;

    if (role == 0) {
        // ---- sfin ----
        su.s.hist4[t] = 0;
        __syncthreads();
        int cnt = cur_s[b * CSTRIDE];
        int base = b * BCAP;
        int sub = (t & 3) * 64;
        for (int j = t; j < cnt; j += 256) atomicAdd(&su.s.hist4[sub + sv6[base + j]], 1);
        __syncthreads();
        if (t < 64) {
            int gid = b * 64 + t;
            if (gid < N_NODES) {
                int v = su.s.hist4[t] + su.s.hist4[64 + t] + su.s.hist4[128 + t] + su.s.hist4[192 + t];
                norm_src[gid] = rsqrtf(fmaxf((float)v, 1.0f));
            }
        }
    } else {
        // ---- dfin ----
        int cnt = cur_d[b * CSTRIDE];
        int base = b * BCAP;
        if (t < 64) { su.d.hist[t] = 0; su.d.cur[t] = 0; }
        su.d.hist4[t] = 0;
        for (int j = t; j < cnt; j += 256) su.d.ebuf[j] = dpk[base + j];
        __syncthreads();
        int sub = (t & 3) * 64;
        for (int j = t; j < cnt; j += 256) atomicAdd(&su.d.hist4[sub + (su.d.ebuf[j] & 63)], 1);
        __syncthreads();
        if (t < 64) {
            int v = su.d.hist4[t] + su.d.hist4[64 + t] + su.d.hist4[128 + t] + su.d.hist4[192 + t];
            su.d.hist[t] = v;
            su.d.seg[t] = v;
        }
        __syncthreads();
#pragma unroll
        for (int off = 1; off < 64; off <<= 1) {
            int xv = 0;
            if (t < 64 && t >= off) xv = su.d.seg[t - off];
            __syncthreads();
            if (t < 64) su.d.seg[t] += xv;
            __syncthreads();
        }
        if (t < 64) {
            int v = su.d.hist[t];
            int excl = su.d.seg[t] - v;
            int gid = b * 64 + t;
            if (gid < N_NODES) {
                rbdeg[gid] = make_int2(base + excl, v);
                norm_dst[gid] = rsqrtf(fmaxf((float)v, 1.0f));
            }
            su.d.seg[t] = excl;
        }
        __syncthreads();
        // csr aliases dpk: safe, bucket staged in LDS, block owns its region.
        for (int j = t; j < cnt; j += 256) {
            int p = su.d.ebuf[j];
            int dlow = p & 63;
            int pos = base + su.d.seg[dlow] + atomicAdd(&su.d.cur[dlow], 1);
            csr[pos] = ((unsigned)p) >> 6;
        }
    }
}

// K3: gemm — hb = bf16(norm_src[r] * (x @ W1T)). LDS-free direct-fragment MFMA.
// 128-thread blocks, 16 rows/wave, ALL 16 x-float4 loads issued up front
// (one memory latency per wave instead of 8 serialized round trips; r2's
// 48-VGPR compile was the smoking gun for serialization).
__global__ __launch_bounds__(128, 3) void gemm_kernel(const float* __restrict__ x,
                                                      const unsigned short* __restrict__ w1t,
                                                      const float* __restrict__ norm_src,
                                                      unsigned short* __restrict__ hb) {
    int t = threadIdx.x;
    int w = t >> 6;
    int l = t & 63;
    int m = l & 15;
    int q = l >> 4;
    int base = (blockIdx.x * 2 + w) * 16;
    if (base >= N_NODES) return;
    const float* xr = &x[(size_t)(base + m) * NFEAT];
    float4 av[16];
#pragma unroll
    for (int i = 0; i < 8; ++i) {
        av[2 * i]     = *(const float4*)(xr + i * 32 + q * 8);
        av[2 * i + 1] = *(const float4*)(xr + i * 32 + q * 8 + 4);
    }
    f32x4 acc[4] = {{0.f, 0.f, 0.f, 0.f}, {0.f, 0.f, 0.f, 0.f},
                    {0.f, 0.f, 0.f, 0.f}, {0.f, 0.f, 0.f, 0.f}};
#pragma unroll
    for (int c8 = 0; c8 < 8; ++c8) {
        int k0 = c8 * 32 + q * 8;
        union { bf16x8 v; unsigned int u[4]; } a;
        a.u[0] = pk2bf(av[2 * c8].x, av[2 * c8].y);
        a.u[1] = pk2bf(av[2 * c8].z, av[2 * c8].w);
        a.u[2] = pk2bf(av[2 * c8 + 1].x, av[2 * c8 + 1].y);
        a.u[3] = pk2bf(av[2 * c8 + 1].z, av[2 * c8 + 1].w);
#pragma unroll
        for (int ct = 0; ct < 4; ++ct) {
            bf16x8 bb = *(const bf16x8*)(&w1t[(ct * 16 + m) * NFEAT + k0]);
            acc[ct] = __builtin_amdgcn_mfma_f32_16x16x32_bf16(a.v, bb, acc[ct], 0, 0, 0);
        }
    }
#pragma unroll
    for (int reg = 0; reg < 4; ++reg) {
        int r = base + q * 4 + reg;
        float ns = norm_src[r];
#pragma unroll
        for (int ct = 0; ct < 4; ++ct)
            hb[(size_t)r * NHID + ct * 16 + m] = f2bf(acc[ct][reg] * ns);
    }
}

// K4: fused layer1, node-major. hb is pre-scaled by norm_src -> per-edge
// work is now just csr load + hb row load + adds (no per-edge norm gather).
__global__ __launch_bounds__(256) void fused1_kernel(const int2* __restrict__ rbdeg,
                                                     const int* __restrict__ csr,
                                                     const unsigned short* __restrict__ hb,
                                                     const float* __restrict__ norm_dst,
                                                     const float* __restrict__ norm_src,
                                                     const float* __restrict__ b1,
                                                     const float* __restrict__ W2,
                                                     float* __restrict__ h2) {
    int gtid = blockIdx.x * blockDim.x + threadIdx.x;
    int node = gtid >> 6;
    int lane = gtid & 63;
    if (node >= N_NODES) return;
    int e8 = lane >> 3, fg = lane & 7;
    int2 rd = rbdeg[node];
    int beg = rd.x;
    int end = beg + rd.y;
    float a0 = 0.f, a1 = 0.f, a2 = 0.f, a3 = 0.f, a4 = 0.f, a5 = 0.f, a6 = 0.f, a7 = 0.f;
    for (int j = beg; j < end; j += 32) {
        int j0 = j + e8, j1 = j0 + 8, j2 = j0 + 16, j3 = j0 + 24;
        uint4 u0 = make_uint4(0u, 0u, 0u, 0u), u1 = make_uint4(0u, 0u, 0u, 0u);
        uint4 u2 = make_uint4(0u, 0u, 0u, 0u), u3 = make_uint4(0u, 0u, 0u, 0u);
        if (j0 < end) u0 = *(const uint4*)(&hb[(size_t)csr[j0] * NHID + fg * 8]);
        if (j1 < end) u1 = *(const uint4*)(&hb[(size_t)csr[j1] * NHID + fg * 8]);
        if (j2 < end) u2 = *(const uint4*)(&hb[(size_t)csr[j2] * NHID + fg * 8]);
        if (j3 < end) u3 = *(const uint4*)(&hb[(size_t)csr[j3] * NHID + fg * 8]);
        a0 += bflo(u0.x) + bflo(u1.x) + bflo(u2.x) + bflo(u3.x);
        a1 += bfhi(u0.x) + bfhi(u1.x) + bfhi(u2.x) + bfhi(u3.x);
        a2 += bflo(u0.y) + bflo(u1.y) + bflo(u2.y) + bflo(u3.y);
        a3 += bfhi(u0.y) + bfhi(u1.y) + bfhi(u2.y) + bfhi(u3.y);
        a4 += bflo(u0.z) + bflo(u1.z) + bflo(u2.z) + bflo(u3.z);
        a5 += bfhi(u0.z) + bfhi(u1.z) + bfhi(u2.z) + bfhi(u3.z);
        a6 += bflo(u0.w) + bflo(u1.w) + bflo(u2.w) + bflo(u3.w);
        a7 += bfhi(u0.w) + bfhi(u1.w) + bfhi(u2.w) + bfhi(u3.w);
    }
#pragma unroll
    for (int off = 8; off <= 32; off <<= 1) {
        a0 += __shfl_xor(a0, off, 64);
        a1 += __shfl_xor(a1, off, 64);
        a2 += __shfl_xor(a2, off, 64);
        a3 += __shfl_xor(a3, off, 64);
        a4 += __shfl_xor(a4, off, 64);
        a5 += __shfl_xor(a5, off, 64);
        a6 += __shfl_xor(a6, off, 64);
        a7 += __shfl_xor(a7, off, 64);
    }
    float nd = norm_dst[node], ns = norm_src[node];
    float4 bv0 = *(const float4*)(&b1[fg * 8]);
    float4 bv1 = *(const float4*)(&b1[fg * 8 + 4]);
    float4 w0 = *(const float4*)(&W2[fg * 16 + 0]);
    float4 w1 = *(const float4*)(&W2[fg * 16 + 4]);
    float4 w2v = *(const float4*)(&W2[fg * 16 + 8]);
    float4 w3 = *(const float4*)(&W2[fg * 16 + 12]);
    float h0 = fmaxf(fmaf(a0, nd, bv0.x), 0.f) * ns;
    float h1 = fmaxf(fmaf(a1, nd, bv0.y), 0.f) * ns;
    float h2f = fmaxf(fmaf(a2, nd, bv0.z), 0.f) * ns;
    float h3 = fmaxf(fmaf(a3, nd, bv0.w), 0.f) * ns;
    float h4 = fmaxf(fmaf(a4, nd, bv1.x), 0.f) * ns;
    float h5 = fmaxf(fmaf(a5, nd, bv1.y), 0.f) * ns;
    float h6 = fmaxf(fmaf(a6, nd, bv1.z), 0.f) * ns;
    float h7 = fmaxf(fmaf(a7, nd, bv1.w), 0.f) * ns;
    float p0 = h0 * w0.x + h1 * w0.z + h2f * w1.x + h3 * w1.z +
               h4 * w2v.x + h5 * w2v.z + h6 * w3.x + h7 * w3.z;
    float p1 = h0 * w0.y + h1 * w0.w + h2f * w1.y + h3 * w1.w +
               h4 * w2v.y + h5 * w2v.w + h6 * w3.y + h7 * w3.w;
#pragma unroll
    for (int off = 1; off <= 4; off <<= 1) {
        p0 += __shfl_xor(p0, off, 64);
        p1 += __shfl_xor(p1, off, 64);
    }
    if (lane == 0) *(float2*)(&h2[node * 2]) = make_float2(p0, p1);
}

// K5: fused layer2: one 16-lane group per node, shfl reduce, log_softmax.
__global__ __launch_bounds__(256) void fused2_kernel(const int2* __restrict__ rbdeg,
                                                     const int* __restrict__ csr,
                                                     const float* __restrict__ h2,
                                                     const float* __restrict__ norm_dst,
                                                     const float* __restrict__ b2,
                                                     float* __restrict__ out) {
    int gtid = blockIdx.x * blockDim.x + threadIdx.x;
    int n = gtid >> 4;
    int l16 = gtid & 15;
    if (n >= N_NODES) return;
    int2 rd = rbdeg[n];
    int beg = rd.x, end = rd.x + rd.y;
    float s0 = 0.f, s1 = 0.f;
    for (int j = beg + l16; j < end; j += 16) {
        float2 v = *(const float2*)(&h2[csr[j] * 2]);
        s0 += v.x;
        s1 += v.y;
    }
#pragma unroll
    for (int off = 1; off <= 8; off <<= 1) {
        s0 += __shfl_xor(s0, off, 16);
        s1 += __shfl_xor(s1, off, 16);
    }
    if (l16 == 0) {
        float nd = norm_dst[n];
        float l0 = fmaf(s0, nd, b2[0]);
        float l1 = fmaf(s1, nd, b2[1]);
        float m = fmaxf(l0, l1);
        float lse = m + logf(expf(l0 - m) + expf(l1 - m));
        *(float2*)(&out[n * 2]) = make_float2(l0 - lse, l1 - lse);
    }
}

extern "C" void kernel_launch(void* const* d_in, const int* in_sizes, int n_in,
                              void* d_out, int out_size, void* d_ws, size_t ws_size,
                              hipStream_t stream) {
    const float* x  = (const float*)d_in[0];
    const int* src  = (const int*)d_in[1];
    const int* dst  = (const int*)d_in[2];
    const float* W1 = (const float*)d_in[3];
    const float* b1 = (const float*)d_in[4];
    const float* W2 = (const float*)d_in[5];
    const float* b2 = (const float*)d_in[6];
    float* out = (float*)d_out;
    float* ws  = (float*)d_ws;
    int*   wsi = (int*)d_ws;

    int*   cur_d    = wsi + OFF_CURD;
    int*   cur_s    = wsi + OFF_CURS;
    int2*  rbdeg    = (int2*)(wsi + OFF_RBD);
    float* norm_dst = ws + OFF_NDST;
    float* norm_src = ws + OFF_NSRC;
    unsigned short* w1t = (unsigned short*)(wsi + OFF_W1T);
    int*   dpk      = wsi + OFF_DPK;
    unsigned char* sv6 = (unsigned char*)(wsi + OFF_SV6);
    int*   csr      = wsi + OFF_DPK;   // alias: dfin rewrites its own bucket in place
    unsigned short* hb = (unsigned short*)(wsi + OFF_HB);
    float* h2       = ws + OFF_H2;

    init_kernel<<<(INIT_N + 255) / 256, 256, 0, stream>>>(W1, cur_d, w1t);
    scatter_kernel<<<NB_EDGE, 256, 0, stream>>>(src, dst, cur_d, cur_s, dpk, sv6);
    fin_kernel<<<NDB * 2, 256, 0, stream>>>(cur_d, cur_s, dpk, sv6, rbdeg, norm_dst, norm_src, csr);
    {
        int tiles = (N_NODES + 15) / 16;           // 3125 wave-tiles
        gemm_kernel<<<(tiles + 1) / 2, 128, 0, stream>>>(x, w1t, norm_src, hb);
    }
    {
        long long threads = (long long)N_NODES * 64;
        fused1_kernel<<<(int)((threads + 255) / 256), 256, 0, stream>>>(
            rbdeg, csr, hb, norm_dst, norm_src, b1, W2, h2);
    }
    {
        long long threads = (long long)N_NODES * 16;
        fused2_kernel<<<(int)((threads + 255) / 256), 256, 0, stream>>>(
            rbdeg, csr, h2, norm_dst, b2, out);
    }
}

// Round 4
// 190.416 us; speedup vs baseline: 1.0333x; 1.0333x over previous
//
#include <hip/hip_runtime.h>
#include <math.h>

#define N_NODES 50000
#define N_EDGES 800000
#define NFEAT 256
#define NHID 64
#define NCLASS 2

// buckets: node>>6 -> 782 buckets of 64 nodes
#define DB 64
#define NDB 782
#define BCAP 1536        // mean 1024, sigma 32 -> +16 sigma headroom
#define EPB 2048         // edges per chunk (8/thread) -> 391 chunks
#define NB_EDGE ((N_EDGES + EPB - 1) / EPB)
#define HISTW (NB_EDGE * NDB)   // 305,762 words per hist/base array

// ---------------- workspace layout (4-byte units) ----------------
#define OFF_CNTD  0         // int[782]  bucket totals (dst)
#define OFF_CNTS  782       // int[782]  bucket totals (src)
#define OFF_RBD   1564      // int2[50000] (row_beg, deg)
#define OFF_NDST  101564    // f32[50000]
#define OFF_NSRC  151564    // f32[50000]
#define OFF_W1T   201564    // bf16[64*256] = 8192 words
#define OFF_HISTD 209756    // int[391*782]
#define OFF_HISTS 515518    // int[391*782]
#define OFF_BASED 821280    // int[391*782]
#define OFF_BASES 1127042   // int[391*782]
#define OFF_DPK   1432804   // int[782*1536=1201152] packed (src<<6|dst&63); csr aliases
#define OFF_SV6   2633956   // uchar[1201152] = 300288 words
#define OFF_HB    2934244   // bf16[50000*64] = 1600000 dwords (norm_src-scaled x@W1)
#define OFF_H2    4534244   // f32[100000]

typedef __attribute__((ext_vector_type(8))) short bf16x8;
typedef __attribute__((ext_vector_type(4))) float f32x4;

static __device__ __forceinline__ unsigned short f2bf(float f) {
    union { float f; unsigned int u; } v; v.f = f;
    return (unsigned short)((v.u + 0x8000u) >> 16);
}
static __device__ __forceinline__ unsigned int pk2bf(float f0, float f1) {
    union { float f; unsigned int u; } a, b; a.f = f0; b.f = f1;
    return __builtin_amdgcn_perm(b.u + 0x8000u, a.u + 0x8000u, 0x07060302u);
}
static __device__ __forceinline__ float bflo(unsigned int u) {
    union { unsigned int x; float f; } v; v.x = u << 16; return v.f;
}
static __device__ __forceinline__ float bfhi(unsigned int u) {
    union { unsigned int x; float f; } v; v.x = u & 0xffff0000u; return v.f;
}

// K0 (seed): role split.
//  blocks [0,391):   per-chunk LDS histograms -> histD/histS[chunk][bin]
//                    (plain coalesced stores; NO global atomics)
//  blocks [391,455): W1 -> W1T bf16
#define W1T_BLOCKS ((NFEAT * NHID + 255) / 256)
__global__ __launch_bounds__(256) void seed_kernel(const int* __restrict__ src,
                                                   const int* __restrict__ dst,
                                                   const float* __restrict__ W1,
                                                   unsigned short* __restrict__ w1t,
                                                   int* __restrict__ histD,
                                                   int* __restrict__ histS) {
    int t = threadIdx.x;
    int bid = blockIdx.x;
    if (bid < NB_EDGE) {
        __shared__ int hd[NDB], hs[NDB];
        for (int i = t; i < NDB; i += 256) { hd[i] = 0; hs[i] = 0; }
        __syncthreads();
        int base = bid * EPB;
#pragma unroll
        for (int i = 0; i < 8; ++i) {
            int e = base + t + i * 256;
            if (e < N_EDGES) {
                atomicAdd(&hd[dst[e] >> 6], 1);
                atomicAdd(&hs[src[e] >> 6], 1);
            }
        }
        __syncthreads();
        for (int i = t; i < NDB; i += 256) {
            histD[bid * NDB + i] = hd[i];
            histS[bid * NDB + i] = hs[i];
        }
    } else {
        int idx = (bid - NB_EDGE) * 256 + t;
        if (idx < NFEAT * NHID) {
            int k = idx >> 6, n = idx & 63;
            w1t[n * NFEAT + k] = f2bf(W1[idx]);
        }
    }
}

// K1 (scan): one wave per (kind, bin). Exclusive prefix over the 391 chunk
// counts -> per-chunk write bases (bucket base b*BCAP folded in) + totals.
__global__ __launch_bounds__(64) void scan_kernel(const int* __restrict__ histD,
                                                  const int* __restrict__ histS,
                                                  int* __restrict__ baseD,
                                                  int* __restrict__ baseS,
                                                  int* __restrict__ cnt_d,
                                                  int* __restrict__ cnt_s) {
    int b = blockIdx.x % NDB;
    int kind = blockIdx.x / NDB;           // 0 = dst, 1 = src
    const int* h = kind ? histS : histD;
    int* bp = kind ? baseS : baseD;
    int lane = threadIdx.x;
    int carry = 0;
    for (int c0 = 0; c0 < NB_EDGE; c0 += 64) {
        int c = c0 + lane;
        int v = (c < NB_EDGE) ? h[c * NDB + b] : 0;
        int inc = v;
#pragma unroll
        for (int off = 1; off < 64; off <<= 1) {
            int u = __shfl_up(inc, off, 64);
            if (lane >= off) inc += u;
        }
        if (c < NB_EDGE) bp[c * NDB + b] = b * BCAP + carry + (inc - v);
        carry += __shfl(inc, 63, 64);
    }
    if (lane == 0) {
        if (kind) cnt_s[b] = carry; else cnt_d[b] = carry;
    }
}

// K2 (scatter): deterministic bases from scan + LDS-local cursors.
// ZERO global atomics; stores are fire-and-forget.
__global__ __launch_bounds__(256) void scatter_kernel(const int* __restrict__ src,
                                                      const int* __restrict__ dst,
                                                      const int* __restrict__ baseD,
                                                      const int* __restrict__ baseS,
                                                      int* __restrict__ dpk,
                                                      unsigned char* __restrict__ sv6) {
    __shared__ int bd[NDB], bs[NDB], cd[NDB], cs[NDB];   // 12.5 KB
    int t = threadIdx.x;
    int chunk = blockIdx.x;
    for (int i = t; i < NDB; i += 256) {
        bd[i] = baseD[chunk * NDB + i];
        bs[i] = baseS[chunk * NDB + i];
        cd[i] = 0; cs[i] = 0;
    }
    __syncthreads();
    int base = chunk * EPB;
#pragma unroll
    for (int i = 0; i < 8; ++i) {
        int e = base + t + i * 256;
        if (e < N_EDGES) {
            int s = src[e], d = dst[e];
            int bin = d >> 6;
            int pos = bd[bin] + atomicAdd(&cd[bin], 1);
            dpk[pos] = (s << 6) | (d & 63);
            int sb = s >> 6;
            int sp = bs[sb] + atomicAdd(&cs[sb], 1);
            sv6[sp] = (unsigned char)(s & 63);
        }
    }
}

// K3: two roles:
//  role 0: sfin -- out-degree hist from sv6 -> norm_src
//  role 1: dfin -- CSR build (in-place over dpk) + norm_dst/rbdeg
union FinShared {
    struct { int ebuf[BCAP]; int hist4[256]; int hist[64]; int seg[64]; int cur[64]; } d;
    struct { int hist4[256]; } s;
};
__global__ __launch_bounds__(256) void fin_kernel(const int* __restrict__ cnt_d,
                                                  const int* __restrict__ cnt_s,
                                                  const int* __restrict__ dpk,
                                                  const unsigned char* __restrict__ sv6,
                                                  int2* __restrict__ rbdeg,
                                                  float* __restrict__ norm_dst,
                                                  float* __restrict__ norm_src,
                                                  int* __restrict__ csr) {
    __shared__ FinShared su;
    int t = threadIdx.x;
    int role = blockIdx.x & 1;
    int b = blockIdx.x >> 1;

    if (role == 0) {
        // ---- sfin ----
        su.s.hist4[t] = 0;
        __syncthreads();
        int cnt = cnt_s[b];
        int base = b * BCAP;
        int sub = (t & 3) * 64;
        for (int j = t; j < cnt; j += 256) atomicAdd(&su.s.hist4[sub + sv6[base + j]], 1);
        __syncthreads();
        if (t < 64) {
            int gid = b * 64 + t;
            if (gid < N_NODES) {
                int v = su.s.hist4[t] + su.s.hist4[64 + t] + su.s.hist4[128 + t] + su.s.hist4[192 + t];
                norm_src[gid] = rsqrtf(fmaxf((float)v, 1.0f));
            }
        }
    } else {
        // ---- dfin ----
        int cnt = cnt_d[b];
        int base = b * BCAP;
        if (t < 64) { su.d.hist[t] = 0; su.d.cur[t] = 0; }
        su.d.hist4[t] = 0;
        for (int j = t; j < cnt; j += 256) su.d.ebuf[j] = dpk[base + j];
        __syncthreads();
        int sub = (t & 3) * 64;
        for (int j = t; j < cnt; j += 256) atomicAdd(&su.d.hist4[sub + (su.d.ebuf[j] & 63)], 1);
        __syncthreads();
        if (t < 64) {
            int v = su.d.hist4[t] + su.d.hist4[64 + t] + su.d.hist4[128 + t] + su.d.hist4[192 + t];
            su.d.hist[t] = v;
            su.d.seg[t] = v;
        }
        __syncthreads();
#pragma unroll
        for (int off = 1; off < 64; off <<= 1) {
            int xv = 0;
            if (t < 64 && t >= off) xv = su.d.seg[t - off];
            __syncthreads();
            if (t < 64) su.d.seg[t] += xv;
            __syncthreads();
        }
        if (t < 64) {
            int v = su.d.hist[t];
            int excl = su.d.seg[t] - v;
            int gid = b * 64 + t;
            if (gid < N_NODES) {
                rbdeg[gid] = make_int2(base + excl, v);
                norm_dst[gid] = rsqrtf(fmaxf((float)v, 1.0f));
            }
            su.d.seg[t] = excl;
        }
        __syncthreads();
        // csr aliases dpk: safe, bucket staged in LDS, block owns its region.
        for (int j = t; j < cnt; j += 256) {
            int p = su.d.ebuf[j];
            int dlow = p & 63;
            int pos = base + su.d.seg[dlow] + atomicAdd(&su.d.cur[dlow], 1);
            csr[pos] = ((unsigned)p) >> 6;
        }
    }
}

// K4: gemm — hb = bf16(norm_src[r] * (x @ W1T)). LDS-free direct-fragment MFMA.
// 128-thread blocks, 16 rows/wave, all 16 x-float4 loads issued up front.
__global__ __launch_bounds__(128, 3) void gemm_kernel(const float* __restrict__ x,
                                                      const unsigned short* __restrict__ w1t,
                                                      const float* __restrict__ norm_src,
                                                      unsigned short* __restrict__ hb) {
    int t = threadIdx.x;
    int w = t >> 6;
    int l = t & 63;
    int m = l & 15;
    int q = l >> 4;
    int base = (blockIdx.x * 2 + w) * 16;
    if (base >= N_NODES) return;
    const float* xr = &x[(size_t)(base + m) * NFEAT];
    float4 av[16];
#pragma unroll
    for (int i = 0; i < 8; ++i) {
        av[2 * i]     = *(const float4*)(xr + i * 32 + q * 8);
        av[2 * i + 1] = *(const float4*)(xr + i * 32 + q * 8 + 4);
    }
    f32x4 acc[4] = {{0.f, 0.f, 0.f, 0.f}, {0.f, 0.f, 0.f, 0.f},
                    {0.f, 0.f, 0.f, 0.f}, {0.f, 0.f, 0.f, 0.f}};
#pragma unroll
    for (int c8 = 0; c8 < 8; ++c8) {
        int k0 = c8 * 32 + q * 8;
        union { bf16x8 v; unsigned int u[4]; } a;
        a.u[0] = pk2bf(av[2 * c8].x, av[2 * c8].y);
        a.u[1] = pk2bf(av[2 * c8].z, av[2 * c8].w);
        a.u[2] = pk2bf(av[2 * c8 + 1].x, av[2 * c8 + 1].y);
        a.u[3] = pk2bf(av[2 * c8 + 1].z, av[2 * c8 + 1].w);
#pragma unroll
        for (int ct = 0; ct < 4; ++ct) {
            bf16x8 bb = *(const bf16x8*)(&w1t[(ct * 16 + m) * NFEAT + k0]);
            acc[ct] = __builtin_amdgcn_mfma_f32_16x16x32_bf16(a.v, bb, acc[ct], 0, 0, 0);
        }
    }
#pragma unroll
    for (int reg = 0; reg < 4; ++reg) {
        int r = base + q * 4 + reg;
        float ns = norm_src[r];
#pragma unroll
        for (int ct = 0; ct < 4; ++ct)
            hb[(size_t)r * NHID + ct * 16 + m] = f2bf(acc[ct][reg] * ns);
    }
}

// K5: fused layer1, node-major. hb pre-scaled by norm_src -> per-edge work
// is csr load + hb row load + adds.
__global__ __launch_bounds__(256) void fused1_kernel(const int2* __restrict__ rbdeg,
                                                     const int* __restrict__ csr,
                                                     const unsigned short* __restrict__ hb,
                                                     const float* __restrict__ norm_dst,
                                                     const float* __restrict__ norm_src,
                                                     const float* __restrict__ b1,
                                                     const float* __restrict__ W2,
                                                     float* __restrict__ h2) {
    int gtid = blockIdx.x * blockDim.x + threadIdx.x;
    int node = gtid >> 6;
    int lane = gtid & 63;
    if (node >= N_NODES) return;
    int e8 = lane >> 3, fg = lane & 7;
    int2 rd = rbdeg[node];
    int beg = rd.x;
    int end = beg + rd.y;
    float a0 = 0.f, a1 = 0.f, a2 = 0.f, a3 = 0.f, a4 = 0.f, a5 = 0.f, a6 = 0.f, a7 = 0.f;
    for (int j = beg; j < end; j += 32) {
        int j0 = j + e8, j1 = j0 + 8, j2 = j0 + 16, j3 = j0 + 24;
        uint4 u0 = make_uint4(0u, 0u, 0u, 0u), u1 = make_uint4(0u, 0u, 0u, 0u);
        uint4 u2 = make_uint4(0u, 0u, 0u, 0u), u3 = make_uint4(0u, 0u, 0u, 0u);
        if (j0 < end) u0 = *(const uint4*)(&hb[(size_t)csr[j0] * NHID + fg * 8]);
        if (j1 < end) u1 = *(const uint4*)(&hb[(size_t)csr[j1] * NHID + fg * 8]);
        if (j2 < end) u2 = *(const uint4*)(&hb[(size_t)csr[j2] * NHID + fg * 8]);
        if (j3 < end) u3 = *(const uint4*)(&hb[(size_t)csr[j3] * NHID + fg * 8]);
        a0 += bflo(u0.x) + bflo(u1.x) + bflo(u2.x) + bflo(u3.x);
        a1 += bfhi(u0.x) + bfhi(u1.x) + bfhi(u2.x) + bfhi(u3.x);
        a2 += bflo(u0.y) + bflo(u1.y) + bflo(u2.y) + bflo(u3.y);
        a3 += bfhi(u0.y) + bfhi(u1.y) + bfhi(u2.y) + bfhi(u3.y);
        a4 += bflo(u0.z) + bflo(u1.z) + bflo(u2.z) + bflo(u3.z);
        a5 += bfhi(u0.z) + bfhi(u1.z) + bfhi(u2.z) + bfhi(u3.z);
        a6 += bflo(u0.w) + bflo(u1.w) + bflo(u2.w) + bflo(u3.w);
        a7 += bfhi(u0.w) + bfhi(u1.w) + bfhi(u2.w) + bfhi(u3.w);
    }
#pragma unroll
    for (int off = 8; off <= 32; off <<= 1) {
        a0 += __shfl_xor(a0, off, 64);
        a1 += __shfl_xor(a1, off, 64);
        a2 += __shfl_xor(a2, off, 64);
        a3 += __shfl_xor(a3, off, 64);
        a4 += __shfl_xor(a4, off, 64);
        a5 += __shfl_xor(a5, off, 64);
        a6 += __shfl_xor(a6, off, 64);
        a7 += __shfl_xor(a7, off, 64);
    }
    float nd = norm_dst[node], ns = norm_src[node];
    float4 bv0 = *(const float4*)(&b1[fg * 8]);
    float4 bv1 = *(const float4*)(&b1[fg * 8 + 4]);
    float4 w0 = *(const float4*)(&W2[fg * 16 + 0]);
    float4 w1 = *(const float4*)(&W2[fg * 16 + 4]);
    float4 w2v = *(const float4*)(&W2[fg * 16 + 8]);
    float4 w3 = *(const float4*)(&W2[fg * 16 + 12]);
    float h0 = fmaxf(fmaf(a0, nd, bv0.x), 0.f) * ns;
    float h1 = fmaxf(fmaf(a1, nd, bv0.y), 0.f) * ns;
    float h2f = fmaxf(fmaf(a2, nd, bv0.z), 0.f) * ns;
    float h3 = fmaxf(fmaf(a3, nd, bv0.w), 0.f) * ns;
    float h4 = fmaxf(fmaf(a4, nd, bv1.x), 0.f) * ns;
    float h5 = fmaxf(fmaf(a5, nd, bv1.y), 0.f) * ns;
    float h6 = fmaxf(fmaf(a6, nd, bv1.z), 0.f) * ns;
    float h7 = fmaxf(fmaf(a7, nd, bv1.w), 0.f) * ns;
    float p0 = h0 * w0.x + h1 * w0.z + h2f * w1.x + h3 * w1.z +
               h4 * w2v.x + h5 * w2v.z + h6 * w3.x + h7 * w3.z;
    float p1 = h0 * w0.y + h1 * w0.w + h2f * w1.y + h3 * w1.w +
               h4 * w2v.y + h5 * w2v.w + h6 * w3.y + h7 * w3.w;
#pragma unroll
    for (int off = 1; off <= 4; off <<= 1) {
        p0 += __shfl_xor(p0, off, 64);
        p1 += __shfl_xor(p1, off, 64);
    }
    if (lane == 0) *(float2*)(&h2[node * 2]) = make_float2(p0, p1);
}

// K6: fused layer2: one 16-lane group per node, shfl reduce, log_softmax.
__global__ __launch_bounds__(256) void fused2_kernel(const int2* __restrict__ rbdeg,
                                                     const int* __restrict__ csr,
                                                     const float* __restrict__ h2,
                                                     const float* __restrict__ norm_dst,
                                                     const float* __restrict__ b2,
                                                     float* __restrict__ out) {
    int gtid = blockIdx.x * blockDim.x + threadIdx.x;
    int n = gtid >> 4;
    int l16 = gtid & 15;
    if (n >= N_NODES) return;
    int2 rd = rbdeg[n];
    int beg = rd.x, end = rd.x + rd.y;
    float s0 = 0.f, s1 = 0.f;
    for (int j = beg + l16; j < end; j += 16) {
        float2 v = *(const float2*)(&h2[csr[j] * 2]);
        s0 += v.x;
        s1 += v.y;
    }
#pragma unroll
    for (int off = 1; off <= 8; off <<= 1) {
        s0 += __shfl_xor(s0, off, 16);
        s1 += __shfl_xor(s1, off, 16);
    }
    if (l16 == 0) {
        float nd = norm_dst[n];
        float l0 = fmaf(s0, nd, b2[0]);
        float l1 = fmaf(s1, nd, b2[1]);
        float m = fmaxf(l0, l1);
        float lse = m + logf(expf(l0 - m) + expf(l1 - m));
        *(float2*)(&out[n * 2]) = make_float2(l0 - lse, l1 - lse);
    }
}

extern "C" void kernel_launch(void* const* d_in, const int* in_sizes, int n_in,
                              void* d_out, int out_size, void* d_ws, size_t ws_size,
                              hipStream_t stream) {
    const float* x  = (const float*)d_in[0];
    const int* src  = (const int*)d_in[1];
    const int* dst  = (const int*)d_in[2];
    const float* W1 = (const float*)d_in[3];
    const float* b1 = (const float*)d_in[4];
    const float* W2 = (const float*)d_in[5];
    const float* b2 = (const float*)d_in[6];
    float* out = (float*)d_out;
    float* ws  = (float*)d_ws;
    int*   wsi = (int*)d_ws;

    int*   cnt_d    = wsi + OFF_CNTD;
    int*   cnt_s    = wsi + OFF_CNTS;
    int2*  rbdeg    = (int2*)(wsi + OFF_RBD);
    float* norm_dst = ws + OFF_NDST;
    float* norm_src = ws + OFF_NSRC;
    unsigned short* w1t = (unsigned short*)(wsi + OFF_W1T);
    int*   histD    = wsi + OFF_HISTD;
    int*   histS    = wsi + OFF_HISTS;
    int*   baseD    = wsi + OFF_BASED;
    int*   baseS    = wsi + OFF_BASES;
    int*   dpk      = wsi + OFF_DPK;
    unsigned char* sv6 = (unsigned char*)(wsi + OFF_SV6);
    int*   csr      = wsi + OFF_DPK;   // alias: dfin rewrites its own bucket in place
    unsigned short* hb = (unsigned short*)(wsi + OFF_HB);
    float* h2       = ws + OFF_H2;

    seed_kernel<<<NB_EDGE + W1T_BLOCKS, 256, 0, stream>>>(src, dst, W1, w1t, histD, histS);
    scan_kernel<<<NDB * 2, 64, 0, stream>>>(histD, histS, baseD, baseS, cnt_d, cnt_s);
    scatter_kernel<<<NB_EDGE, 256, 0, stream>>>(src, dst, baseD, baseS, dpk, sv6);
    fin_kernel<<<NDB * 2, 256, 0, stream>>>(cnt_d, cnt_s, dpk, sv6, rbdeg, norm_dst, norm_src, csr);
    {
        int tiles = (N_NODES + 15) / 16;           // 3125 wave-tiles
        gemm_kernel<<<(tiles + 1) / 2, 128, 0, stream>>>(x, w1t, norm_src, hb);
    }
    {
        long long threads = (long long)N_NODES * 64;
        fused1_kernel<<<(int)((threads + 255) / 256), 256, 0, stream>>>(
            rbdeg, csr, hb, norm_dst, norm_src, b1, W2, h2);
    }
    {
        long long threads = (long long)N_NODES * 16;
        fused2_kernel<<<(int)((threads + 255) / 256), 256, 0, stream>>>(
            rbdeg, csr, h2, norm_dst, b2, out);
    }
}

// Round 5
// 170.609 us; speedup vs baseline: 1.1533x; 1.1161x over previous
//
#include <hip/hip_runtime.h>
#include <math.h>

#define N_NODES 50000
#define N_EDGES 800000
#define NFEAT 256
#define NHID 64
#define NCLASS 2

// buckets: node>>6 -> 782 buckets of 64 nodes
#define DB 64
#define NDB 782
#define BCAP 1536        // csr per-bucket spacing (mean 1024, +16 sigma)
#define EPB 2048         // edges per scatter chunk (8/thread) -> 391 chunks
#define NB_EDGE ((N_EDGES + EPB - 1) / EPB)
#define NSUB 16          // sub-cursors per bucket: atomic chain 391 -> ~25
#define SUBCAP 160       // per-(bucket,sub) slots: mean 65, sigma 8 -> +11.6 sigma
#define SUBREG (NSUB * SUBCAP)   // 2560 per bucket
#define CSTR 8           // cursor padding: 4 counters per 128B line

// ---------------- workspace layout (4-byte units) ----------------
#define OFF_CURD 0         // int[NDB*NSUB*CSTR = 100096]
#define OFF_CURS 100096    // int[100096]
#define OFF_RBD  200192    // int2[50000] (row_beg, deg)
#define OFF_NDST 300192    // f32[50000]
#define OFF_NSRC 350192    // f32[50000]
#define OFF_W1T  400192    // bf16[64*256] = 8192 words
#define OFF_DPK  408384    // int[782*2560 = 2001920] packed (src<<6|dst&63)
#define OFF_SV6  2410304   // uchar[782*2560] = 500480 words
#define OFF_CSR  2910784   // int[782*1536 = 1201152]
#define OFF_HB   4111936   // bf16[50000*64] = 1600000 dwords (UN-normed x@W1)
#define OFF_H2   5711936   // f32[100000]

typedef __attribute__((ext_vector_type(8))) short bf16x8;
typedef __attribute__((ext_vector_type(4))) float f32x4;

static __device__ __forceinline__ unsigned short f2bf(float f) {
    union { float f; unsigned int u; } v; v.f = f;
    return (unsigned short)((v.u + 0x8000u) >> 16);
}
static __device__ __forceinline__ unsigned int pk2bf(float f0, float f1) {
    union { float f; unsigned int u; } a, b; a.f = f0; b.f = f1;
    return __builtin_amdgcn_perm(b.u + 0x8000u, a.u + 0x8000u, 0x07060302u);
}
static __device__ __forceinline__ float bflo(unsigned int u) {
    union { unsigned int x; float f; } v; v.x = u << 16; return v.f;
}
static __device__ __forceinline__ float bfhi(unsigned int u) {
    union { unsigned int x; float f; } v; v.x = u & 0xffff0000u; return v.f;
}

// K0: zero sub-cursor arrays (contiguous), W1 -> W1T bf16
#define INIT_CUR (2 * NDB * NSUB * CSTR)
#define INIT_N (INIT_CUR + NFEAT * NHID)
__global__ __launch_bounds__(256) void init_kernel(const float* __restrict__ W1,
                                                   int* __restrict__ cursors,
                                                   unsigned short* __restrict__ w1t) {
    int g = blockIdx.x * 256 + threadIdx.x;
    if (g < INIT_CUR) {
        cursors[g] = 0;
    } else if (g < INIT_N) {
        int idx = g - INIT_CUR;
        int k = idx >> 6, n = idx & 63;
        w1t[n * NFEAT + k] = f2bf(W1[idx]);
    }
}

// K1: interleaved roles (bid%3==0 -> scatter, else gemm); 391+782=1173 blocks.
//  scatter: single-pass binning. LDS hist -> ONE global atomic per (bin,sub)
//           per block (chain depth ~25 via NSUB=16 sub-cursors) -> LDS-cursor
//           scatter into the block's own sub-region. No long fabric chains.
//  gemm:    hb = bf16(x @ W1T), UN-normed (no norm_src dep -> overlaps scatter).
//           LDS-free direct-fragment MFMA, all 16 x-float4 loads prefetched.
struct SgShared { int hd[NDB], bd[NDB], cd[NDB], hs[NDB], bs[NDB], cs[NDB]; };  // 18.8 KB
__global__ __launch_bounds__(256) void sg_kernel(const int* __restrict__ src,
                                                 const int* __restrict__ dst,
                                                 const float* __restrict__ x,
                                                 const unsigned short* __restrict__ w1t,
                                                 int* __restrict__ cur_d,
                                                 int* __restrict__ cur_s,
                                                 int* __restrict__ dpk,
                                                 unsigned char* __restrict__ sv6,
                                                 unsigned short* __restrict__ hb) {
    __shared__ SgShared su;
    int t = threadIdx.x;
    int bid = blockIdx.x;
    if (bid % 3 == 0) {
        // ---- scatter role ----
        int chunk = bid / 3;
        int sub = chunk & (NSUB - 1);
        for (int i = t; i < NDB; i += 256) { su.hd[i] = 0; su.cd[i] = 0; su.hs[i] = 0; su.cs[i] = 0; }
        __syncthreads();
        int base = chunk * EPB;
        int ls[8], ld[8];
#pragma unroll
        for (int i = 0; i < 8; ++i) {
            int e = base + t + i * 256;
            ls[i] = (e < N_EDGES) ? src[e] : -1;
            ld[i] = (e < N_EDGES) ? dst[e] : -1;
            if (ld[i] >= 0) {
                atomicAdd(&su.hd[ld[i] >> 6], 1);
                atomicAdd(&su.hs[ls[i] >> 6], 1);
            }
        }
        __syncthreads();
        for (int i = t; i < NDB; i += 256) {
            if (su.hd[i]) su.bd[i] = atomicAdd(&cur_d[(sub * NDB + i) * CSTR], su.hd[i]);
            if (su.hs[i]) su.bs[i] = atomicAdd(&cur_s[(sub * NDB + i) * CSTR], su.hs[i]);
        }
        __syncthreads();
#pragma unroll
        for (int i = 0; i < 8; ++i) {
            if (ld[i] >= 0) {
                int bin = ld[i] >> 6;
                int pos = su.bd[bin] + atomicAdd(&su.cd[bin], 1);
                dpk[(bin * NSUB + sub) * SUBCAP + pos] = (ls[i] << 6) | (ld[i] & 63);
                int sbin = ls[i] >> 6;
                int spos = su.bs[sbin] + atomicAdd(&su.cs[sbin], 1);
                sv6[(sbin * NSUB + sub) * SUBCAP + spos] = (unsigned char)(ls[i] & 63);
            }
        }
    } else {
        // ---- gemm role ----
        const int b = (bid / 3) * 2 + (bid % 3) - 1;   // 0..781
        const int row0 = b * 64;
        const int w = t >> 6;
        const int l = t & 63;
        const int m = l & 15;
        const int q = l >> 4;
        int grow = row0 + w * 16 + m;
        const float* xr = &x[(size_t)((grow < N_NODES) ? grow : 0) * NFEAT];
        float4 av[16];
#pragma unroll
        for (int i = 0; i < 8; ++i) {
            av[2 * i]     = *(const float4*)(xr + i * 32 + q * 8);
            av[2 * i + 1] = *(const float4*)(xr + i * 32 + q * 8 + 4);
        }
        f32x4 acc[4] = {{0.f, 0.f, 0.f, 0.f}, {0.f, 0.f, 0.f, 0.f},
                        {0.f, 0.f, 0.f, 0.f}, {0.f, 0.f, 0.f, 0.f}};
#pragma unroll
        for (int c8 = 0; c8 < 8; ++c8) {
            int k0 = c8 * 32 + q * 8;
            union { bf16x8 v; unsigned int u[4]; } a;
            a.u[0] = pk2bf(av[2 * c8].x, av[2 * c8].y);
            a.u[1] = pk2bf(av[2 * c8].z, av[2 * c8].w);
            a.u[2] = pk2bf(av[2 * c8 + 1].x, av[2 * c8 + 1].y);
            a.u[3] = pk2bf(av[2 * c8 + 1].z, av[2 * c8 + 1].w);
#pragma unroll
            for (int ct = 0; ct < 4; ++ct) {
                bf16x8 bb = *(const bf16x8*)(&w1t[(ct * 16 + m) * NFEAT + k0]);
                acc[ct] = __builtin_amdgcn_mfma_f32_16x16x32_bf16(a.v, bb, acc[ct], 0, 0, 0);
            }
        }
#pragma unroll
        for (int reg = 0; reg < 4; ++reg) {
            int r = row0 + w * 16 + q * 4 + reg;
            if (r < N_NODES) {
#pragma unroll
                for (int ct = 0; ct < 4; ++ct)
                    hb[(size_t)r * NHID + ct * 16 + m] = f2bf(acc[ct][reg]);
            }
        }
    }
}

// K2: two roles:
//  role 0: sfin -- out-degree hist over the bucket's NSUB sv6 sub-ranges -> norm_src
//  role 1: dfin -- stage NSUB dpk sub-ranges to LDS, hist/prefix -> CSR (own array)
//                  + norm_dst/rbdeg
union FinShared {
    struct { int ebuf[BCAP]; int hist4[256]; int hist[64]; int seg[64]; int cur[64]; } d;
    struct { int hist4[256]; } s;
};
__global__ __launch_bounds__(256) void fin_kernel(const int* __restrict__ cur_d,
                                                  const int* __restrict__ cur_s,
                                                  const int* __restrict__ dpk,
                                                  const unsigned char* __restrict__ sv6,
                                                  int2* __restrict__ rbdeg,
                                                  float* __restrict__ norm_dst,
                                                  float* __restrict__ norm_src,
                                                  int* __restrict__ csr) {
    __shared__ FinShared su;
    int t = threadIdx.x;
    int role = blockIdx.x & 1;
    int b = blockIdx.x >> 1;

    if (role == 0) {
        // ---- sfin ----
        su.s.hist4[t] = 0;
        __syncthreads();
        int sub4 = (t & 3) * 64;
        for (int sub = 0; sub < NSUB; ++sub) {
            int c = cur_s[(sub * NDB + b) * CSTR];
            c = (c < SUBCAP) ? c : SUBCAP;
            int gb = (b * NSUB + sub) * SUBCAP;
            for (int j = t; j < c; j += 256) atomicAdd(&su.s.hist4[sub4 + sv6[gb + j]], 1);
        }
        __syncthreads();
        if (t < 64) {
            int gid = b * 64 + t;
            if (gid < N_NODES) {
                int v = su.s.hist4[t] + su.s.hist4[64 + t] + su.s.hist4[128 + t] + su.s.hist4[192 + t];
                norm_src[gid] = rsqrtf(fmaxf((float)v, 1.0f));
            }
        }
    } else {
        // ---- dfin ----
        int base = b * BCAP;
        if (t < 64) { su.d.hist[t] = 0; su.d.cur[t] = 0; }
        su.d.hist4[t] = 0;
        int off = 0;
        for (int sub = 0; sub < NSUB; ++sub) {
            int c = cur_d[(sub * NDB + b) * CSTR];
            c = (c < SUBCAP) ? c : SUBCAP;
            int gb = (b * NSUB + sub) * SUBCAP;
            for (int j = t; j < c; j += 256) su.d.ebuf[off + j] = dpk[gb + j];
            off += c;
        }
        int cnt = off;
        __syncthreads();
        int sub4 = (t & 3) * 64;
        for (int j = t; j < cnt; j += 256) atomicAdd(&su.d.hist4[sub4 + (su.d.ebuf[j] & 63)], 1);
        __syncthreads();
        if (t < 64) {
            int v = su.d.hist4[t] + su.d.hist4[64 + t] + su.d.hist4[128 + t] + su.d.hist4[192 + t];
            su.d.hist[t] = v;
            su.d.seg[t] = v;
        }
        __syncthreads();
#pragma unroll
        for (int offp = 1; offp < 64; offp <<= 1) {
            int xv = 0;
            if (t < 64 && t >= offp) xv = su.d.seg[t - offp];
            __syncthreads();
            if (t < 64) su.d.seg[t] += xv;
            __syncthreads();
        }
        if (t < 64) {
            int v = su.d.hist[t];
            int excl = su.d.seg[t] - v;
            int gid = b * 64 + t;
            if (gid < N_NODES) {
                rbdeg[gid] = make_int2(base + excl, v);
                norm_dst[gid] = rsqrtf(fmaxf((float)v, 1.0f));
            }
            su.d.seg[t] = excl;
        }
        __syncthreads();
        for (int j = t; j < cnt; j += 256) {
            int p = su.d.ebuf[j];
            int dlow = p & 63;
            int pos = base + su.d.seg[dlow] + atomicAdd(&su.d.cur[dlow], 1);
            csr[pos] = ((unsigned)p) >> 6;
        }
    }
}

// K3: fused layer1, node-major. hb UN-normed -> per-edge norm_src[s] via fmaf
// (norm_src is 200 KB, L2-resident). 32 edges in flight per wave.
__global__ __launch_bounds__(256) void fused1_kernel(const int2* __restrict__ rbdeg,
                                                     const int* __restrict__ csr,
                                                     const unsigned short* __restrict__ hb,
                                                     const float* __restrict__ norm_dst,
                                                     const float* __restrict__ norm_src,
                                                     const float* __restrict__ b1,
                                                     const float* __restrict__ W2,
                                                     float* __restrict__ h2) {
    int gtid = blockIdx.x * blockDim.x + threadIdx.x;
    int node = gtid >> 6;
    int lane = gtid & 63;
    if (node >= N_NODES) return;
    int e8 = lane >> 3, fg = lane & 7;
    int2 rd = rbdeg[node];
    int beg = rd.x;
    int end = beg + rd.y;
    float a0 = 0.f, a1 = 0.f, a2 = 0.f, a3 = 0.f, a4 = 0.f, a5 = 0.f, a6 = 0.f, a7 = 0.f;
    for (int j = beg; j < end; j += 32) {
        int j0 = j + e8, j1 = j0 + 8, j2 = j0 + 16, j3 = j0 + 24;
        uint4 u0 = make_uint4(0u, 0u, 0u, 0u), u1 = make_uint4(0u, 0u, 0u, 0u);
        uint4 u2 = make_uint4(0u, 0u, 0u, 0u), u3 = make_uint4(0u, 0u, 0u, 0u);
        float ns0 = 0.f, ns1 = 0.f, ns2 = 0.f, ns3 = 0.f;
        if (j0 < end) {
            int s = csr[j0];
            ns0 = norm_src[s];
            u0 = *(const uint4*)(&hb[(size_t)s * NHID + fg * 8]);
        }
        if (j1 < end) {
            int s = csr[j1];
            ns1 = norm_src[s];
            u1 = *(const uint4*)(&hb[(size_t)s * NHID + fg * 8]);
        }
        if (j2 < end) {
            int s = csr[j2];
            ns2 = norm_src[s];
            u2 = *(const uint4*)(&hb[(size_t)s * NHID + fg * 8]);
        }
        if (j3 < end) {
            int s = csr[j3];
            ns3 = norm_src[s];
            u3 = *(const uint4*)(&hb[(size_t)s * NHID + fg * 8]);
        }
        a0 = fmaf(ns0, bflo(u0.x), fmaf(ns1, bflo(u1.x), fmaf(ns2, bflo(u2.x), fmaf(ns3, bflo(u3.x), a0))));
        a1 = fmaf(ns0, bfhi(u0.x), fmaf(ns1, bfhi(u1.x), fmaf(ns2, bfhi(u2.x), fmaf(ns3, bfhi(u3.x), a1))));
        a2 = fmaf(ns0, bflo(u0.y), fmaf(ns1, bflo(u1.y), fmaf(ns2, bflo(u2.y), fmaf(ns3, bflo(u3.y), a2))));
        a3 = fmaf(ns0, bfhi(u0.y), fmaf(ns1, bfhi(u1.y), fmaf(ns2, bfhi(u2.y), fmaf(ns3, bfhi(u3.y), a3))));
        a4 = fmaf(ns0, bflo(u0.z), fmaf(ns1, bflo(u1.z), fmaf(ns2, bflo(u2.z), fmaf(ns3, bflo(u3.z), a4))));
        a5 = fmaf(ns0, bfhi(u0.z), fmaf(ns1, bfhi(u1.z), fmaf(ns2, bfhi(u2.z), fmaf(ns3, bfhi(u3.z), a5))));
        a6 = fmaf(ns0, bflo(u0.w), fmaf(ns1, bflo(u1.w), fmaf(ns2, bflo(u2.w), fmaf(ns3, bflo(u3.w), a6))));
        a7 = fmaf(ns0, bfhi(u0.w), fmaf(ns1, bfhi(u1.w), fmaf(ns2, bfhi(u2.w), fmaf(ns3, bfhi(u3.w), a7))));
    }
#pragma unroll
    for (int off = 8; off <= 32; off <<= 1) {
        a0 += __shfl_xor(a0, off, 64);
        a1 += __shfl_xor(a1, off, 64);
        a2 += __shfl_xor(a2, off, 64);
        a3 += __shfl_xor(a3, off, 64);
        a4 += __shfl_xor(a4, off, 64);
        a5 += __shfl_xor(a5, off, 64);
        a6 += __shfl_xor(a6, off, 64);
        a7 += __shfl_xor(a7, off, 64);
    }
    float nd = norm_dst[node], ns = norm_src[node];
    float4 bv0 = *(const float4*)(&b1[fg * 8]);
    float4 bv1 = *(const float4*)(&b1[fg * 8 + 4]);
    float4 w0 = *(const float4*)(&W2[fg * 16 + 0]);
    float4 w1 = *(const float4*)(&W2[fg * 16 + 4]);
    float4 w2v = *(const float4*)(&W2[fg * 16 + 8]);
    float4 w3 = *(const float4*)(&W2[fg * 16 + 12]);
    float h0 = fmaxf(fmaf(a0, nd, bv0.x), 0.f) * ns;
    float h1 = fmaxf(fmaf(a1, nd, bv0.y), 0.f) * ns;
    float h2f = fmaxf(fmaf(a2, nd, bv0.z), 0.f) * ns;
    float h3 = fmaxf(fmaf(a3, nd, bv0.w), 0.f) * ns;
    float h4 = fmaxf(fmaf(a4, nd, bv1.x), 0.f) * ns;
    float h5 = fmaxf(fmaf(a5, nd, bv1.y), 0.f) * ns;
    float h6 = fmaxf(fmaf(a6, nd, bv1.z), 0.f) * ns;
    float h7 = fmaxf(fmaf(a7, nd, bv1.w), 0.f) * ns;
    float p0 = h0 * w0.x + h1 * w0.z + h2f * w1.x + h3 * w1.z +
               h4 * w2v.x + h5 * w2v.z + h6 * w3.x + h7 * w3.z;
    float p1 = h0 * w0.y + h1 * w0.w + h2f * w1.y + h3 * w1.w +
               h4 * w2v.y + h5 * w2v.w + h6 * w3.y + h7 * w3.w;
#pragma unroll
    for (int off = 1; off <= 4; off <<= 1) {
        p0 += __shfl_xor(p0, off, 64);
        p1 += __shfl_xor(p1, off, 64);
    }
    if (lane == 0) *(float2*)(&h2[node * 2]) = make_float2(p0, p1);
}

// K4: fused layer2: one 16-lane group per node, shfl reduce, log_softmax.
__global__ __launch_bounds__(256) void fused2_kernel(const int2* __restrict__ rbdeg,
                                                     const int* __restrict__ csr,
                                                     const float* __restrict__ h2,
                                                     const float* __restrict__ norm_dst,
                                                     const float* __restrict__ b2,
                                                     float* __restrict__ out) {
    int gtid = blockIdx.x * blockDim.x + threadIdx.x;
    int n = gtid >> 4;
    int l16 = gtid & 15;
    if (n >= N_NODES) return;
    int2 rd = rbdeg[n];
    int beg = rd.x, end = rd.x + rd.y;
    float s0 = 0.f, s1 = 0.f;
    for (int j = beg + l16; j < end; j += 16) {
        float2 v = *(const float2*)(&h2[csr[j] * 2]);
        s0 += v.x;
        s1 += v.y;
    }
#pragma unroll
    for (int off = 1; off <= 8; off <<= 1) {
        s0 += __shfl_xor(s0, off, 16);
        s1 += __shfl_xor(s1, off, 16);
    }
    if (l16 == 0) {
        float nd = norm_dst[n];
        float l0 = fmaf(s0, nd, b2[0]);
        float l1 = fmaf(s1, nd, b2[1]);
        float m = fmaxf(l0, l1);
        float lse = m + logf(expf(l0 - m) + expf(l1 - m));
        *(float2*)(&out[n * 2]) = make_float2(l0 - lse, l1 - lse);
    }
}

extern "C" void kernel_launch(void* const* d_in, const int* in_sizes, int n_in,
                              void* d_out, int out_size, void* d_ws, size_t ws_size,
                              hipStream_t stream) {
    const float* x  = (const float*)d_in[0];
    const int* src  = (const int*)d_in[1];
    const int* dst  = (const int*)d_in[2];
    const float* W1 = (const float*)d_in[3];
    const float* b1 = (const float*)d_in[4];
    const float* W2 = (const float*)d_in[5];
    const float* b2 = (const float*)d_in[6];
    float* out = (float*)d_out;
    float* ws  = (float*)d_ws;
    int*   wsi = (int*)d_ws;

    int*   cur_d    = wsi + OFF_CURD;
    int*   cur_s    = wsi + OFF_CURS;
    int2*  rbdeg    = (int2*)(wsi + OFF_RBD);
    float* norm_dst = ws + OFF_NDST;
    float* norm_src = ws + OFF_NSRC;
    unsigned short* w1t = (unsigned short*)(wsi + OFF_W1T);
    int*   dpk      = wsi + OFF_DPK;
    unsigned char* sv6 = (unsigned char*)(wsi + OFF_SV6);
    int*   csr      = wsi + OFF_CSR;
    unsigned short* hb = (unsigned short*)(wsi + OFF_HB);
    float* h2       = ws + OFF_H2;

    init_kernel<<<(INIT_N + 255) / 256, 256, 0, stream>>>(W1, cur_d, w1t);
    sg_kernel<<<NB_EDGE * 3, 256, 0, stream>>>(src, dst, x, w1t, cur_d, cur_s, dpk, sv6, hb);
    fin_kernel<<<NDB * 2, 256, 0, stream>>>(cur_d, cur_s, dpk, sv6, rbdeg, norm_dst, norm_src, csr);
    {
        long long threads = (long long)N_NODES * 64;
        fused1_kernel<<<(int)((threads + 255) / 256), 256, 0, stream>>>(
            rbdeg, csr, hb, norm_dst, norm_src, b1, W2, h2);
    }
    {
        long long threads = (long long)N_NODES * 16;
        fused2_kernel<<<(int)((threads + 255) / 256), 256, 0, stream>>>(
            rbdeg, csr, h2, norm_dst, b2, out);
    }
}